// Round 8
// baseline (203.478 us; speedup 1.0000x reference)
//
#include <hip/hip_runtime.h>
#include <math.h>

#define BB 4
#define NN 512
#define DD 256
#define HH 8
#define BND (BB*NN*DD)

typedef _Float16 h2 __attribute__((ext_vector_type(2)));
typedef _Float16 f16x4 __attribute__((ext_vector_type(4)));
typedef float    f32x4 __attribute__((ext_vector_type(4)));

static __device__ __forceinline__ h2 u2h(unsigned u) { return __builtin_bit_cast(h2, u); }
// RNE pack
static __device__ __forceinline__ h2 pk2(float a, float b) {
    h2 r; r[0] = (_Float16)a; r[1] = (_Float16)b; return r;
}
static __device__ __forceinline__ unsigned pk2u(float a, float b) {
    return __builtin_bit_cast(unsigned, pk2(a, b));
}
static __device__ __forceinline__ float dot2(h2 a, h2 b, float c) {
    return __builtin_amdgcn_fdot2(a, b, c, false);
}

constexpr int RB = 8;

// ---------------- QKV projection ----------------
// q16 (f16), k16 (f16 pre-scaled by 1/sqrt(32)), v16 packed [j/2][c] f16 pairs
__global__ __launch_bounds__(256) void qkv_proj(
    const float* __restrict__ hg, const int* __restrict__ mask,
    const float* __restrict__ Wq, const float* __restrict__ Wk, const float* __restrict__ Wv,
    _Float16* __restrict__ q16, _Float16* __restrict__ k16, _Float16* __restrict__ v16h)
{
    __shared__ float hsT[DD][RB];
    const int t = threadIdx.x;
    const int r0 = blockIdx.x * RB;
    #pragma unroll
    for (int rr = 0; rr < RB; ++rr) {
        float x = hg[(size_t)(r0 + rr) * DD + t];
        if (mask[r0 + rr] == 0) x = 0.f;
        hsT[t][rr] = x;
    }
    __syncthreads();
    float aq[RB], ak[RB], av[RB];
    #pragma unroll
    for (int rr = 0; rr < RB; ++rr) { aq[rr] = 0.f; ak[rr] = 0.f; av[rr] = 0.f; }
    for (int d = 0; d < DD; ++d) {
        const float wq = Wq[d*DD + t];
        const float wk = Wk[d*DD + t];
        const float wv = Wv[d*DD + t];
        const float4 h0 = *(const float4*)&hsT[d][0];
        const float4 h1 = *(const float4*)&hsT[d][4];
        const float hv[8] = {h0.x,h0.y,h0.z,h0.w,h1.x,h1.y,h1.z,h1.w};
        #pragma unroll
        for (int rr = 0; rr < RB; ++rr) {
            aq[rr] = fmaf(hv[rr], wq, aq[rr]);
            ak[rr] = fmaf(hv[rr], wk, ak[rr]);
            av[rr] = fmaf(hv[rr], wv, av[rr]);
        }
    }
    const float qscale = 0.17677669529663687f; // 1/sqrt(32)
    #pragma unroll
    for (int rr = 0; rr < RB; ++rr) {
        const int r = r0 + rr;
        q16[(size_t)r*DD + t] = (_Float16)aq[rr];
        k16[(size_t)r*DD + t] = (_Float16)(ak[rr] * qscale);
        v16h[((size_t)(r >> 1)*DD + t)*2 + (r & 1)] = (_Float16)av[rr];
    }
}

// ---------------- kernel A: bias-MLP + QK via MFMA ----------------
// block = (b, i). 4 waves; wave w handles j-tiles w, w+4, ... (8 tiles of 16 j).
// Swapped GEMMs: C^T layouts chain register-locally L1 -> L2.
//   L1: M=hid(16 tiles), N=16 pairs, K=16 (dx,dy,dist,team,bias1,0...)
//   L2: M=16 (8 heads pad), N=16 pairs, K=16*16 hid + 16*16 qk-extension
// Output: logits f16 packed j-pairs -> logitsH[b][i][h][j/2] dwords.
__global__ __launch_bounds__(256, 2) void bias_qk(
    const _Float16* __restrict__ q16, const _Float16* __restrict__ k16,
    const float* __restrict__ p, const int* __restrict__ side, const int* __restrict__ mask,
    const float* __restrict__ W1, const float* __restrict__ b1,
    const float* __restrict__ W2, const float* __restrict__ b2,
    unsigned* __restrict__ logitsH)
{
    __shared__ float xl[4][16][8];   // per-wave transpose buffer

    const int t  = threadIdx.x;
    const int w  = t >> 6;
    const int l  = t & 63;
    const int lo = l & 15;
    const int g  = l >> 4;
    const int b  = blockIdx.x >> 9;
    const int i  = blockIdx.x & 511;

    const f16x4 z4 = {(_Float16)0.f,(_Float16)0.f,(_Float16)0.f,(_Float16)0.f};
    const f32x4 zf = {0.f,0.f,0.f,0.f};

    // ---- A1 fragments: W1ext^T[hid][k]  (k: 0..3 feats, 4 bias, 5..15 zero) ----
    f16x4 a1[16];
    #pragma unroll
    for (int m = 0; m < 16; ++m) {
        const int hid = m*16 + lo;
        f16x4 v = z4;
        const float w0 = W1[hid], w1 = W1[256+hid], w2 = W1[512+hid], w3 = W1[768+hid];
        const float bb1 = b1[hid];
        if (g == 0) { v[0]=(_Float16)w0; v[1]=(_Float16)w1; v[2]=(_Float16)w2; v[3]=(_Float16)w3; }
        else if (g == 1) { v[0]=(_Float16)bb1; }
        a1[m] = v;
    }
    // ---- A2 fragments: W2^T[h][hid], h=lo (valid <8), k-step s covers hid s*16+g*4+{0..3} ----
    f16x4 a2[16];
    #pragma unroll
    for (int s = 0; s < 16; ++s) {
        const int kb4 = s*16 + g*4;
        const int hs  = lo & 7;
        f16x4 v;
        v[0] = (_Float16)W2[(kb4+0)*HH + hs];
        v[1] = (_Float16)W2[(kb4+1)*HH + hs];
        v[2] = (_Float16)W2[(kb4+2)*HH + hs];
        v[3] = (_Float16)W2[(kb4+3)*HH + hs];
        a2[s] = (lo < 8) ? v : z4;
    }
    // ---- QK A fragments: head-masked q_i. step s2: c = s2*16+g*4+{0..3}; nonzero iff lo == s2>>1 ----
    const _Float16* qrow = q16 + (size_t)(b*NN + i)*DD;
    f16x4 aq[16];
    #pragma unroll
    for (int s2 = 0; s2 < 16; ++s2) {
        const f16x4 qv = *(const f16x4*)(qrow + s2*16 + g*4);
        aq[s2] = (lo == (s2 >> 1)) ? qv : z4;
    }
    // b2 per-lane (epilogue rows h = g*4+bb, valid g<2)
    float b2v[4];
    #pragma unroll
    for (int bb = 0; bb < 4; ++bb) {
        const int idx = (g*4 + bb) & 7;
        const float vb2 = b2[idx];
        b2v[bb] = (g < 2) ? vb2 : 0.f;
    }

    const float pix = p[(size_t)(b*NN + i)*2 + 0];
    const float piy = p[(size_t)(b*NN + i)*2 + 1];
    const int   si  = side[b*NN + i];

    for (int jt = w; jt < 32; jt += 4) {
        const int j0 = jt*16;
        const int j  = j0 + lo;
        const float px = p[(size_t)(b*NN + j)*2 + 0];
        const float py = p[(size_t)(b*NN + j)*2 + 1];
        const int   sj = side[b*NN + j];
        const int   mk = mask[b*NN + j];
        const float dx = pix - px;
        const float dy = piy - py;
        const float di = fmaxf(sqrtf(dx*dx + dy*dy), 1e-6f);
        const float tm = (si == sj) ? 1.f : 0.f;

        // feat B-fragment: col=pair(lo), k=g*4+{0..3}
        f16x4 bf = z4;
        if (g == 0) { bf[0]=(_Float16)dx; bf[1]=(_Float16)dy; bf[2]=(_Float16)di; bf[3]=(_Float16)tm; }
        else if (g == 1) { bf[0]=(_Float16)1.f; }

        // QK B-fragments: k16[c][j] (issue loads early)
        const _Float16* krow = k16 + (size_t)(b*NN + j)*DD;
        f16x4 kb[16];
        #pragma unroll
        for (int s2 = 0; s2 < 16; ++s2)
            kb[s2] = *(const f16x4*)(krow + s2*16 + g*4);

        // L1: 16 independent MFMA
        f32x4 c1[16];
        #pragma unroll
        for (int m = 0; m < 16; ++m)
            c1[m] = __builtin_amdgcn_mfma_f32_16x16x16f16(a1[m], bf, zf, 0, 0, 0);

        // L2: relu+cvt in-register; 2-way acc split for ILP
        f32x4 acc0 = zf, acc1 = zf;
        #pragma unroll
        for (int s = 0; s < 16; ++s) {
            f16x4 hb;
            hb[0] = (_Float16)fmaxf(c1[s][0], 0.f);
            hb[1] = (_Float16)fmaxf(c1[s][1], 0.f);
            hb[2] = (_Float16)fmaxf(c1[s][2], 0.f);
            hb[3] = (_Float16)fmaxf(c1[s][3], 0.f);
            if (s & 1) acc1 = __builtin_amdgcn_mfma_f32_16x16x16f16(a2[s], hb, acc1, 0, 0, 0);
            else       acc0 = __builtin_amdgcn_mfma_f32_16x16x16f16(a2[s], hb, acc0, 0, 0, 0);
        }
        // QK extension
        #pragma unroll
        for (int s2 = 0; s2 < 16; ++s2) {
            if (s2 & 1) acc1 = __builtin_amdgcn_mfma_f32_16x16x16f16(aq[s2], kb[s2], acc1, 0, 0, 0);
            else        acc0 = __builtin_amdgcn_mfma_f32_16x16x16f16(aq[s2], kb[s2], acc0, 0, 0, 0);
        }

        // epilogue: logits[h][j] = acc + b2 + keymask; lanes l<32 hold h=g*4+bb (0..7)
        const float km = mk ? 0.f : -3.0e4f;
        if (l < 32) {
            #pragma unroll
            for (int bb = 0; bb < 4; ++bb)
                xl[w][lo][g*4 + bb] = acc0[bb] + acc1[bb] + b2v[bb] + km;
        }
        asm volatile("s_waitcnt lgkmcnt(0)" ::: "memory");
        __builtin_amdgcn_sched_barrier(0);
        // transpose-read: lane -> (h = l>>3, jp = l&7); pack j-pair, store
        {
            const int hh = l >> 3;
            const int jp = l & 7;
            const unsigned dw = pk2u(xl[w][2*jp][hh], xl[w][2*jp+1][hh]);
            logitsH[((size_t)((b*NN + i)*HH + hh))*(NN/2) + jt*8 + jp] = dw;
        }
        asm volatile("s_waitcnt lgkmcnt(0)" ::: "memory");
        __builtin_amdgcn_sched_barrier(0);
    }
}

// ---------------- kernel B: softmax + PV ----------------
// block = (b, 4 query rows), 256 threads; thread t owns j-pair (2t, 2t+1).
__global__ __launch_bounds__(256, 4) void attn_sm(
    const unsigned* __restrict__ logitsH, const unsigned* __restrict__ v16p,
    float* __restrict__ ao)
{
    __shared__ unsigned Lgh[32][260];
    __shared__ float red[32][8];
    __shared__ float mx[32];
    __shared__ float rs[32];

    const int t  = threadIdx.x;
    const int b  = blockIdx.x / (NN/4);
    const int i0 = (blockIdx.x % (NN/4)) * 4;

    // load packed logits (coalesced dwords)
    #pragma unroll
    for (int ii = 0; ii < 4; ++ii)
        #pragma unroll
        for (int hh = 0; hh < HH; ++hh)
            Lgh[ii*8 + hh][t] = logitsH[((size_t)((b*NN + i0 + ii)*HH + hh))*(NN/2) + t];
    __syncthreads();

    // ---- softmax over j for each of 32 rows (ii,hh); 8 threads per row ----
    const int combo = t >> 3;
    const int sub   = t & 7;
    {
        h2 pm = u2h(0xFC00FC00u);
        for (int jp = sub; jp < NN/2; jp += 8)
            pm = __builtin_elementwise_max(pm, u2h(Lgh[combo][jp]));
        red[combo][sub] = fmaxf((float)pm[0], (float)pm[1]);
    }
    __syncthreads();
    if (t < 32) {
        float mm = red[t][0];
        #pragma unroll
        for (int s = 1; s < 8; ++s) mm = fmaxf(mm, red[t][s]);
        mx[t] = mm;
    }
    __syncthreads();
    {
        const float M = mx[combo];
        float s = 0.f;
        for (int jp = sub; jp < NN/2; jp += 8) {
            const h2 lg = u2h(Lgh[combo][jp]);
            const float e0 = __expf((float)lg[0] - M);
            const float e1 = __expf((float)lg[1] - M);
            s += e0 + e1;
            Lgh[combo][jp] = pk2u(e0, e1);
        }
        red[combo][sub] = s;
    }
    __syncthreads();
    if (t < 32) {
        float s = 0.f;
        #pragma unroll
        for (int ss = 0; ss < 8; ++ss) s += red[t][ss];
        rs[t] = 1.f / s;
    }
    __syncthreads();

    // ---- PV: thread t owns output column c = t ----
    {
        const int c = t;
        const int hh = c >> 5;
        const unsigned* vb = v16p + (size_t)b*(NN/2)*DD + c;
        float o[4] = {0.f, 0.f, 0.f, 0.f};
        for (int jp = 0; jp < NN/2; ++jp) {
            const h2 vp = u2h(vb[(size_t)jp*DD]);
            #pragma unroll
            for (int ii = 0; ii < 4; ++ii)
                o[ii] = dot2(u2h(Lgh[ii*8 + hh][jp]), vp, o[ii]);
        }
        #pragma unroll
        for (int ii = 0; ii < 4; ++ii)
            ao[(size_t)(b*NN + i0 + ii)*DD + c] = o[ii] * rs[ii*8 + hh];
    }
}

// ---------------- output projection: out = ao @ Wo ----------------
__global__ __launch_bounds__(256) void oproj(
    const float* __restrict__ X, const float* __restrict__ W, float* __restrict__ Y)
{
    __shared__ float xsT[DD][RB];
    const int t = threadIdx.x;
    const int r0 = blockIdx.x * RB;
    #pragma unroll
    for (int rr = 0; rr < RB; ++rr)
        xsT[t][rr] = X[(size_t)(r0 + rr)*DD + t];
    __syncthreads();
    float a[RB];
    #pragma unroll
    for (int rr = 0; rr < RB; ++rr) a[rr] = 0.f;
    for (int d = 0; d < DD; ++d) {
        const float w = W[d*DD + t];
        const float4 h0 = *(const float4*)&xsT[d][0];
        const float4 h1 = *(const float4*)&xsT[d][4];
        const float hv[8] = {h0.x,h0.y,h0.z,h0.w,h1.x,h1.y,h1.z,h1.w};
        #pragma unroll
        for (int rr = 0; rr < RB; ++rr)
            a[rr] = fmaf(hv[rr], w, a[rr]);
    }
    #pragma unroll
    for (int rr = 0; rr < RB; ++rr)
        Y[(size_t)(r0 + rr)*DD + t] = a[rr];
}

extern "C" void kernel_launch(void* const* d_in, const int* in_sizes, int n_in,
                              void* d_out, int out_size, void* d_ws, size_t ws_size,
                              hipStream_t stream) {
    const float* hg   = (const float*)d_in[0];
    const float* p    = (const float*)d_in[1];
    const int*   side = (const int*)d_in[2];
    const int*   mask = (const int*)d_in[3];
    const float* Wq   = (const float*)d_in[4];
    const float* Wk   = (const float*)d_in[5];
    const float* Wv   = (const float*)d_in[6];
    const float* Wo   = (const float*)d_in[7];
    const float* W1   = (const float*)d_in[8];
    const float* b1   = (const float*)d_in[9];
    const float* W2   = (const float*)d_in[10];
    const float* b2   = (const float*)d_in[11];

    float* ws = (float*)d_ws;
    float* ao = ws;                                   // BND f32
    _Float16* q16 = (_Float16*)(ws + BND);            // BND f16
    _Float16* k16 = q16 + BND;                        // BND f16
    _Float16* v16 = k16 + BND;                        // BND f16 (packed pairs)
    unsigned* logitsH = (unsigned*)(v16 + BND);       // B*N*H*(N/2) dwords = 16.8MB

    qkv_proj<<<(BB*NN)/RB, 256, 0, stream>>>(hg, mask, Wq, Wk, Wv, q16, k16, v16);
    bias_qk<<<BB*NN, 256, 0, stream>>>(q16, k16, p, side, mask, W1, b1, W2, b2, logitsH);
    attn_sm<<<BB*(NN/4), 256, 0, stream>>>(logitsH, (const unsigned*)v16, ao);
    oproj<<<(BB*NN)/RB, 256, 0, stream>>>(ao, Wo, (float*)d_out);
}

// Round 9
// 144.311 us; speedup vs baseline: 1.4100x; 1.4100x over previous
//
#include <hip/hip_runtime.h>
#include <math.h>

#define BB 4
#define NN 512
#define DD 256
#define HH 8
#define BND (BB*NN*DD)

typedef _Float16 h2 __attribute__((ext_vector_type(2)));
typedef _Float16 f16x4 __attribute__((ext_vector_type(4)));
typedef float    f32x4 __attribute__((ext_vector_type(4)));

static __device__ __forceinline__ h2 u2h(unsigned u) { return __builtin_bit_cast(h2, u); }
// RNE pack
static __device__ __forceinline__ h2 pk2(float a, float b) {
    h2 r; r[0] = (_Float16)a; r[1] = (_Float16)b; return r;
}
static __device__ __forceinline__ unsigned pk2u(float a, float b) {
    return __builtin_bit_cast(unsigned, pk2(a, b));
}
static __device__ __forceinline__ float dot2(h2 a, h2 b, float c) {
    return __builtin_amdgcn_fdot2(a, b, c, false);
}

constexpr int RB = 4;   // rows per block in the row-GEMM kernels (512 blocks -> 2 waves/SIMD)

// ---------------- QKV projection ----------------
// q16 (f16), k16 (f16 pre-scaled by 1/sqrt(32)), v16 packed [j/2][c] f16 pairs
__global__ __launch_bounds__(256) void qkv_proj(
    const float* __restrict__ hg, const int* __restrict__ mask,
    const float* __restrict__ Wq, const float* __restrict__ Wk, const float* __restrict__ Wv,
    _Float16* __restrict__ q16, _Float16* __restrict__ k16, _Float16* __restrict__ v16h)
{
    __shared__ float hsT[DD][RB];
    const int t = threadIdx.x;
    const int r0 = blockIdx.x * RB;
    #pragma unroll
    for (int rr = 0; rr < RB; ++rr) {
        float x = hg[(size_t)(r0 + rr) * DD + t];
        if (mask[r0 + rr] == 0) x = 0.f;
        hsT[t][rr] = x;
    }
    __syncthreads();
    float aq[RB], ak[RB], av[RB];
    #pragma unroll
    for (int rr = 0; rr < RB; ++rr) { aq[rr] = 0.f; ak[rr] = 0.f; av[rr] = 0.f; }
    for (int d = 0; d < DD; ++d) {
        const float wq = Wq[d*DD + t];
        const float wk = Wk[d*DD + t];
        const float wv = Wv[d*DD + t];
        const float4 h0 = *(const float4*)&hsT[d][0];
        const float hv[4] = {h0.x, h0.y, h0.z, h0.w};
        #pragma unroll
        for (int rr = 0; rr < RB; ++rr) {
            aq[rr] = fmaf(hv[rr], wq, aq[rr]);
            ak[rr] = fmaf(hv[rr], wk, ak[rr]);
            av[rr] = fmaf(hv[rr], wv, av[rr]);
        }
    }
    const float qscale = 0.17677669529663687f; // 1/sqrt(32)
    #pragma unroll
    for (int rr = 0; rr < RB; ++rr) {
        const int r = r0 + rr;
        q16[(size_t)r*DD + t] = (_Float16)aq[rr];
        k16[(size_t)r*DD + t] = (_Float16)(ak[rr] * qscale);
        v16h[((size_t)(r >> 1)*DD + t)*2 + (r & 1)] = (_Float16)av[rr];
    }
}

// ---------------- kernel A: bias-MLP via MFMA + QK via dot2 (VALU) ----------------
// block = (b, i). 4 waves; wave w handles j-tiles w, w+4, ... (8 tiles of 16 j).
// Per tile: L1 (16 MFMA, interleaved relu+cvt_pkrtz) -> L2 (16 MFMA, 4-way acc).
// QK runs on the VALU (idle while matrix pipe works): lane (lo,g) owns j=j0+lo,
// heads 2g and 2g+1 (16 dot2 each over the 32-dim head slice).
__global__ __launch_bounds__(256, 3) void bias_qk(
    const _Float16* __restrict__ q16, const _Float16* __restrict__ k16,
    const float* __restrict__ p, const int* __restrict__ side, const int* __restrict__ mask,
    const float* __restrict__ W1, const float* __restrict__ b1,
    const float* __restrict__ W2, const float* __restrict__ b2,
    unsigned* __restrict__ logitsH)
{
    __shared__ float xl[4][16][9];   // bias transpose buffer (padded: conflict-free)
    __shared__ float xq[4][16][9];   // qk transpose buffer

    const int t  = threadIdx.x;
    const int w  = t >> 6;
    const int l  = t & 63;
    const int lo = l & 15;
    const int g  = l >> 4;
    const int b  = blockIdx.x >> 9;
    const int i  = blockIdx.x & 511;

    const f16x4 z4 = {(_Float16)0.f,(_Float16)0.f,(_Float16)0.f,(_Float16)0.f};
    const f32x4 zf = {0.f,0.f,0.f,0.f};

    // A1 fragments: W1ext^T[hid][k] (k: 0..3 feats, 4 bias, 5..15 zero)
    f16x4 a1[16];
    #pragma unroll
    for (int m = 0; m < 16; ++m) {
        const int hid = m*16 + lo;
        f16x4 v = z4;
        const float w0 = W1[hid], w1 = W1[256+hid], w2 = W1[512+hid], w3 = W1[768+hid];
        const float bb1 = b1[hid];
        if (g == 0) { v[0]=(_Float16)w0; v[1]=(_Float16)w1; v[2]=(_Float16)w2; v[3]=(_Float16)w3; }
        else if (g == 1) { v[0]=(_Float16)bb1; }
        a1[m] = v;
    }
    // A2 fragments: W2^T[h][hid], h=lo (valid <8), k-step s covers hid s*16+g*4+{0..3}
    f16x4 a2[16];
    #pragma unroll
    for (int s = 0; s < 16; ++s) {
        const int kb4 = s*16 + g*4;
        const int hs  = lo & 7;
        f16x4 v;
        v[0] = (_Float16)W2[(kb4+0)*HH + hs];
        v[1] = (_Float16)W2[(kb4+1)*HH + hs];
        v[2] = (_Float16)W2[(kb4+2)*HH + hs];
        v[3] = (_Float16)W2[(kb4+3)*HH + hs];
        a2[s] = (lo < 8) ? v : z4;
    }
    // b2 per-lane (epilogue rows h = g*4+bb, valid g<2)
    float b2v[4];
    #pragma unroll
    for (int bb = 0; bb < 4; ++bb) {
        const float vb2 = b2[(g*4 + bb) & 7];
        b2v[bb] = (g < 2) ? vb2 : 0.f;
    }
    // q slices for VALU-QK: heads 2g, 2g+1 (uniform per block row, broadcast loads)
    const uint2* qrow = (const uint2*)(q16 + (size_t)(b*NN + i)*DD);  // 8B units
    uint2 qq0[8], qq1[8];
    #pragma unroll
    for (int m = 0; m < 8; ++m) {
        qq0[m] = qrow[(2*g)*8 + m];
        qq1[m] = qrow[(2*g+1)*8 + m];
    }

    const float pix = p[(size_t)(b*NN + i)*2 + 0];
    const float piy = p[(size_t)(b*NN + i)*2 + 1];
    const int   si  = side[b*NN + i];

    for (int jt = w; jt < 32; jt += 4) {
        const int j = jt*16 + lo;

        // issue QK k-loads early (in flight during the MFMA loop)
        const uint2* krow = (const uint2*)(k16 + (size_t)(b*NN + j)*DD);
        uint2 kk0[8], kk1[8];
        #pragma unroll
        for (int m = 0; m < 8; ++m) {
            kk0[m] = krow[(2*g)*8 + m];
            kk1[m] = krow[(2*g+1)*8 + m];
        }

        const float px = p[(size_t)(b*NN + j)*2 + 0];
        const float py = p[(size_t)(b*NN + j)*2 + 1];
        const int   sj = side[b*NN + j];
        const int   mk = mask[b*NN + j];
        const float dx = pix - px;
        const float dy = piy - py;
        const float di = fmaxf(sqrtf(dx*dx + dy*dy), 1e-6f);
        const float tm = (si == sj) ? 1.f : 0.f;

        // feature B-fragment: col=pair(lo), k=g*4+{0..3}
        f16x4 bf = z4;
        if (g == 0) { bf[0]=(_Float16)dx; bf[1]=(_Float16)dy; bf[2]=(_Float16)di; bf[3]=(_Float16)tm; }
        else if (g == 1) { bf[0]=(_Float16)1.f; }

        // interleaved L1 -> relu/cvt -> L2 (c1 transient, 4-way acc rotation)
        f32x4 accv[4] = {zf, zf, zf, zf};
        #pragma unroll
        for (int s = 0; s < 16; ++s) {
            const f32x4 c1 = __builtin_amdgcn_mfma_f32_16x16x16f16(a1[s], bf, zf, 0, 0, 0);
            // relu in f32, pack with cvt_pkrtz (RTZ on hidden only: negligible error)
            const h2 p01 = __builtin_bit_cast(h2, __builtin_amdgcn_cvt_pkrtz(fmaxf(c1[0],0.f), fmaxf(c1[1],0.f)));
            const h2 p23 = __builtin_bit_cast(h2, __builtin_amdgcn_cvt_pkrtz(fmaxf(c1[2],0.f), fmaxf(c1[3],0.f)));
            f16x4 hb;
            hb[0] = p01[0]; hb[1] = p01[1]; hb[2] = p23[0]; hb[3] = p23[1];
            accv[s & 3] = __builtin_amdgcn_mfma_f32_16x16x16f16(a2[s], hb, accv[s & 3], 0, 0, 0);
        }

        // QK on the VALU (k loads long since in flight)
        float qk0 = 0.f, qk1 = 0.f;
        #pragma unroll
        for (int m = 0; m < 8; ++m) {
            qk0 = dot2(u2h(kk0[m].x), u2h(qq0[m].x), qk0);
            qk0 = dot2(u2h(kk0[m].y), u2h(qq0[m].y), qk0);
            qk1 = dot2(u2h(kk1[m].x), u2h(qq1[m].x), qk1);
            qk1 = dot2(u2h(kk1[m].y), u2h(qq1[m].y), qk1);
        }

        // epilogue: bias rows h=g*4+bb (lanes l<32), qk all lanes
        const float km = mk ? 0.f : -3.0e4f;
        if (l < 32) {
            #pragma unroll
            for (int bb = 0; bb < 4; ++bb)
                xl[w][lo][g*4 + bb] = accv[0][bb] + accv[1][bb] + accv[2][bb] + accv[3][bb]
                                      + b2v[bb] + km;
        }
        xq[w][lo][2*g]     = qk0;
        xq[w][lo][2*g + 1] = qk1;
        asm volatile("s_waitcnt lgkmcnt(0)" ::: "memory");
        __builtin_amdgcn_sched_barrier(0);
        // transpose-read: lane -> (h = l>>3, jp = l&7); pack j-pair, store
        {
            const int hh = l >> 3;
            const int jp = l & 7;
            const float v0 = xl[w][2*jp][hh]     + xq[w][2*jp][hh];
            const float v1 = xl[w][2*jp + 1][hh] + xq[w][2*jp + 1][hh];
            logitsH[((size_t)((b*NN + i)*HH + hh))*(NN/2) + jt*8 + jp] = pk2u(v0, v1);
        }
        asm volatile("s_waitcnt lgkmcnt(0)" ::: "memory");
        __builtin_amdgcn_sched_barrier(0);
    }
}

// ---------------- kernel B: softmax + PV ----------------
// block = (b, 2 query rows), 256 threads; thread t owns j-pair (2t, 2t+1).
// 1024 blocks -> 4 blocks/CU (latency-bound kernel: TLP hides L2 loads).
__global__ __launch_bounds__(256, 4) void attn_sm(
    const unsigned* __restrict__ logitsH, const unsigned* __restrict__ v16p,
    float* __restrict__ ao)
{
    __shared__ unsigned Lgh[16][260];
    __shared__ float red[16][16];
    __shared__ float mx[16];
    __shared__ float rs[16];

    const int t  = threadIdx.x;
    const int b  = blockIdx.x / (NN/2);
    const int i0 = (blockIdx.x % (NN/2)) * 2;

    // load packed logits (coalesced dwords)
    #pragma unroll
    for (int ii = 0; ii < 2; ++ii)
        #pragma unroll
        for (int hh = 0; hh < HH; ++hh)
            Lgh[ii*8 + hh][t] = logitsH[((size_t)((b*NN + i0 + ii)*HH + hh))*(NN/2) + t];
    __syncthreads();

    // ---- softmax over j for each of 16 rows (ii,hh); 16 threads per row ----
    const int combo = t >> 4;
    const int sub   = t & 15;
    {
        h2 pm = u2h(0xFC00FC00u);
        for (int jp = sub; jp < NN/2; jp += 16)
            pm = __builtin_elementwise_max(pm, u2h(Lgh[combo][jp]));
        red[combo][sub] = fmaxf((float)pm[0], (float)pm[1]);
    }
    __syncthreads();
    if (t < 16) {
        float mm = red[t][0];
        #pragma unroll
        for (int s = 1; s < 16; ++s) mm = fmaxf(mm, red[t][s]);
        mx[t] = mm;
    }
    __syncthreads();
    {
        const float M = mx[combo];
        float s = 0.f;
        for (int jp = sub; jp < NN/2; jp += 16) {
            const h2 lg = u2h(Lgh[combo][jp]);
            const float e0 = __expf((float)lg[0] - M);
            const float e1 = __expf((float)lg[1] - M);
            s += e0 + e1;
            Lgh[combo][jp] = pk2u(e0, e1);
        }
        red[combo][sub] = s;
    }
    __syncthreads();
    if (t < 16) {
        float s = 0.f;
        #pragma unroll
        for (int ss = 0; ss < 16; ++ss) s += red[t][ss];
        rs[t] = 1.f / s;
    }
    __syncthreads();

    // ---- PV: thread t owns output column c = t ----
    {
        const int c = t;
        const int hh = c >> 5;
        const unsigned* vb = v16p + (size_t)b*(NN/2)*DD + c;
        float o[2] = {0.f, 0.f};
        for (int jp = 0; jp < NN/2; ++jp) {
            const h2 vp = u2h(vb[(size_t)jp*DD]);
            #pragma unroll
            for (int ii = 0; ii < 2; ++ii)
                o[ii] = dot2(u2h(Lgh[ii*8 + hh][jp]), vp, o[ii]);
        }
        #pragma unroll
        for (int ii = 0; ii < 2; ++ii)
            ao[(size_t)(b*NN + i0 + ii)*DD + c] = o[ii] * rs[ii*8 + hh];
    }
}

// ---------------- output projection: out = ao @ Wo ----------------
__global__ __launch_bounds__(256) void oproj(
    const float* __restrict__ X, const float* __restrict__ W, float* __restrict__ Y)
{
    __shared__ float xsT[DD][RB];
    const int t = threadIdx.x;
    const int r0 = blockIdx.x * RB;
    #pragma unroll
    for (int rr = 0; rr < RB; ++rr)
        xsT[t][rr] = X[(size_t)(r0 + rr)*DD + t];
    __syncthreads();
    float a[RB];
    #pragma unroll
    for (int rr = 0; rr < RB; ++rr) a[rr] = 0.f;
    for (int d = 0; d < DD; ++d) {
        const float w = W[d*DD + t];
        const float4 h0 = *(const float4*)&xsT[d][0];
        const float hv[4] = {h0.x, h0.y, h0.z, h0.w};
        #pragma unroll
        for (int rr = 0; rr < RB; ++rr)
            a[rr] = fmaf(hv[rr], w, a[rr]);
    }
    #pragma unroll
    for (int rr = 0; rr < RB; ++rr)
        Y[(size_t)(r0 + rr)*DD + t] = a[rr];
}

extern "C" void kernel_launch(void* const* d_in, const int* in_sizes, int n_in,
                              void* d_out, int out_size, void* d_ws, size_t ws_size,
                              hipStream_t stream) {
    const float* hg   = (const float*)d_in[0];
    const float* p    = (const float*)d_in[1];
    const int*   side = (const int*)d_in[2];
    const int*   mask = (const int*)d_in[3];
    const float* Wq   = (const float*)d_in[4];
    const float* Wk   = (const float*)d_in[5];
    const float* Wv   = (const float*)d_in[6];
    const float* Wo   = (const float*)d_in[7];
    const float* W1   = (const float*)d_in[8];
    const float* b1   = (const float*)d_in[9];
    const float* W2   = (const float*)d_in[10];
    const float* b2   = (const float*)d_in[11];

    float* ws = (float*)d_ws;
    float* ao = ws;                                   // BND f32
    _Float16* q16 = (_Float16*)(ws + BND);            // BND f16
    _Float16* k16 = q16 + BND;                        // BND f16
    _Float16* v16 = k16 + BND;                        // BND f16 (packed pairs)
    unsigned* logitsH = (unsigned*)(v16 + BND);       // B*N*H*(N/2) dwords

    qkv_proj<<<(BB*NN)/RB, 256, 0, stream>>>(hg, mask, Wq, Wk, Wv, q16, k16, v16);
    bias_qk<<<BB*NN, 256, 0, stream>>>(q16, k16, p, side, mask, W1, b1, W2, b2, logitsH);
    attn_sm<<<BB*(NN/2), 256, 0, stream>>>(logitsH, (const unsigned*)v16, ao);
    oproj<<<(BB*NN)/RB, 256, 0, stream>>>(ao, Wo, (float*)d_out);
}

// Round 11
// 101.587 us; speedup vs baseline: 2.0030x; 1.4206x over previous
//
#include <hip/hip_runtime.h>
#include <math.h>

#define BB 4
#define NN 512
#define DD 256
#define HH 8
#define BND (BB*NN*DD)

typedef _Float16 h2 __attribute__((ext_vector_type(2)));
typedef _Float16 f16x4 __attribute__((ext_vector_type(4)));
typedef float    f32x4 __attribute__((ext_vector_type(4)));

static __device__ __forceinline__ h2 u2h(unsigned u) { return __builtin_bit_cast(h2, u); }
// RNE pack (features/logits)
static __device__ __forceinline__ h2 pk2(float a, float b) {
    h2 r; r[0] = (_Float16)a; r[1] = (_Float16)b; return r;
}
static __device__ __forceinline__ unsigned pk2u(float a, float b) {
    return __builtin_bit_cast(unsigned, pk2(a, b));
}
// RTZ pack (hidden only — R9-proven)
static __device__ __forceinline__ h2 pkz(float a, float b) {
    return __builtin_bit_cast(h2, __builtin_amdgcn_cvt_pkrtz(a, b));
}
static __device__ __forceinline__ float dot2(h2 a, h2 b, float c) {
    return __builtin_amdgcn_fdot2(a, b, c, false);
}

constexpr int RB = 4;

// ---------------- QKV projection ----------------
__global__ __launch_bounds__(256) void qkv_proj(
    const float* __restrict__ hg, const int* __restrict__ mask,
    const float* __restrict__ Wq, const float* __restrict__ Wk, const float* __restrict__ Wv,
    _Float16* __restrict__ q16, _Float16* __restrict__ k16, _Float16* __restrict__ v16h)
{
    __shared__ float hsT[DD][RB];
    const int t = threadIdx.x;
    const int r0 = blockIdx.x * RB;
    #pragma unroll
    for (int rr = 0; rr < RB; ++rr) {
        float x = hg[(size_t)(r0 + rr) * DD + t];
        if (mask[r0 + rr] == 0) x = 0.f;
        hsT[t][rr] = x;
    }
    __syncthreads();
    float aq[RB], ak[RB], av[RB];
    #pragma unroll
    for (int rr = 0; rr < RB; ++rr) { aq[rr] = 0.f; ak[rr] = 0.f; av[rr] = 0.f; }
    for (int d = 0; d < DD; ++d) {
        const float wq = Wq[d*DD + t];
        const float wk = Wk[d*DD + t];
        const float wv = Wv[d*DD + t];
        const float4 h0 = *(const float4*)&hsT[d][0];
        const float hv[4] = {h0.x, h0.y, h0.z, h0.w};
        #pragma unroll
        for (int rr = 0; rr < RB; ++rr) {
            aq[rr] = fmaf(hv[rr], wq, aq[rr]);
            ak[rr] = fmaf(hv[rr], wk, ak[rr]);
            av[rr] = fmaf(hv[rr], wv, av[rr]);
        }
    }
    const float qscale = 0.17677669529663687f; // 1/sqrt(32)
    #pragma unroll
    for (int rr = 0; rr < RB; ++rr) {
        const int r = r0 + rr;
        q16[(size_t)r*DD + t] = (_Float16)aq[rr];
        k16[(size_t)r*DD + t] = (_Float16)(ak[rr] * qscale);
        v16h[((size_t)(r >> 1)*DD + t)*2 + (r & 1)] = (_Float16)av[rr];
    }
}

// ---------------- kernel A: bias-MLP + QK, i-tile=16, all-MFMA ----------------
// block = (b, i-tile of 16, j-quarter of 128). 512 blocks, 4 waves.
// Wave w owns j-tiles w and w+4 (16 j each) fully — no inter-wave sync.
// Per tile: QK = 16 dense MFMA (8 heads, K=32); MLP = 16 pair-groups (group =
// fixed i): 16 L1 + 16 L2 MFMA with in-register relu+cvt. Merge via LDS rmw.
__global__ __launch_bounds__(256, 2) void bias_qk(
    const _Float16* __restrict__ q16, const _Float16* __restrict__ k16,
    const float* __restrict__ p, const int* __restrict__ side, const int* __restrict__ mask,
    const float* __restrict__ W1, const float* __restrict__ b1,
    const float* __restrict__ W2, const float* __restrict__ b2,
    unsigned* __restrict__ logitsH)
{
    __shared__ float bsm[4][16*132];   // per-wave logits [i][h*16 + j], stride 132
    __shared__ float pis[16][2];
    __shared__ int   sis[16];

    const int t  = threadIdx.x;
    const int w  = t >> 6;
    const int l  = t & 63;
    const int lo = l & 15;
    const int g  = l >> 4;

    const int bid = blockIdx.x;
    const int b   = bid >> 7;
    const int it  = (bid >> 2) & 31;
    const int jq  = bid & 3;
    const int i0  = it * 16;
    const int j0  = jq * 128;

    if (t < 16) {
        const float2 pp = ((const float2*)p)[b*NN + i0 + t];
        pis[t][0] = pp.x; pis[t][1] = pp.y;
        sis[t] = side[b*NN + i0 + t];
    }
    __syncthreads();

    const f16x4 z4 = {(_Float16)0.f,(_Float16)0.f,(_Float16)0.f,(_Float16)0.f};
    const f32x4 zf = {0.f,0.f,0.f,0.f};
    const h2 zz = {(_Float16)0.f, (_Float16)0.f};

    // A1: W1ext^T[hid][k]  (k: 0..3 feats, 4 bias-one, 5..15 zero)
    f16x4 a1[16];
    #pragma unroll
    for (int m = 0; m < 16; ++m) {
        const int hid = m*16 + lo;
        f16x4 v = z4;
        const float w0 = W1[hid], w1 = W1[256+hid], w2 = W1[512+hid], w3 = W1[768+hid];
        const float bb1 = b1[hid];
        if (g == 0) { v[0]=(_Float16)w0; v[1]=(_Float16)w1; v[2]=(_Float16)w2; v[3]=(_Float16)w3; }
        else if (g == 1) { v[0]=(_Float16)bb1; }
        a1[m] = v;
    }
    // A2: W2^T[h][hid], rows 8..15 zero
    f16x4 a2[16];
    #pragma unroll
    for (int s = 0; s < 16; ++s) {
        const int kb4 = s*16 + g*4;
        const int hs  = lo & 7;
        f16x4 v;
        v[0] = (_Float16)W2[(kb4+0)*HH + hs];
        v[1] = (_Float16)W2[(kb4+1)*HH + hs];
        v[2] = (_Float16)W2[(kb4+2)*HH + hs];
        v[3] = (_Float16)W2[(kb4+3)*HH + hs];
        a2[s] = (lo < 8) ? v : z4;
    }
    // b2 addend for epilogue rows h = g*4+r (only l<32 stores)
    float b2v[4];
    #pragma unroll
    for (int r = 0; r < 4; ++r) b2v[r] = (g < 2) ? b2[(g*4 + r) & 7] : 0.f;

    // q A-fragments (row i = i0+lo, k = g*4+reg within 16-slice), once per block
    const _Float16* qbase = q16 + (size_t)(b*NN + i0 + lo)*DD;
    f16x4 qf[8][2];
    #pragma unroll
    for (int h = 0; h < 8; ++h) {
        qf[h][0] = *(const f16x4*)(qbase + h*32 + g*4);
        qf[h][1] = *(const f16x4*)(qbase + h*32 + 16 + g*4);
    }

    float* bw = &bsm[w][0];

    for (int jt = w; jt < 8; jt += 4) {
        const int jb = j0 + jt*16;
        const int j  = jb + lo;                 // this lane's key column

        const _Float16* kbase = k16 + (size_t)(b*NN + j)*DD;
        const float2 pj = ((const float2*)p)[b*NN + j];
        const int   sj  = side[b*NN + j];
        const float km  = mask[b*NN + j] ? 0.f : -3.0e4f;

        // QK: 8 heads x (K=32 as 2 MFMA). B: col j = lo, k = g*4+reg.
        f32x4 qk[8];
        #pragma unroll
        for (int h = 0; h < 8; ++h) {
            const f16x4 kf0 = *(const f16x4*)(kbase + h*32 + g*4);
            const f16x4 kf1 = *(const f16x4*)(kbase + h*32 + 16 + g*4);
            f32x4 a = __builtin_amdgcn_mfma_f32_16x16x16f16(qf[h][0], kf0, zf, 0, 0, 0);
            qk[h]   = __builtin_amdgcn_mfma_f32_16x16x16f16(qf[h][1], kf1, a, 0, 0, 0);
        }

        // MLP pair-groups: group = query row i, cols = 16 j
        #pragma unroll 4
        for (int i = 0; i < 16; ++i) {
            const float pix = pis[i][0], piy = pis[i][1];
            const int   sii = sis[i];
            const float dx = pix - pj.x;
            const float dy = piy - pj.y;
            const float di = fmaxf(sqrtf(dx*dx + dy*dy), 1e-6f);
            const float tm = (sii == sj) ? 1.f : 0.f;
            const h2 fA = pk2(dx, dy);   // RNE on features
            const h2 fB = pk2(di, tm);
            f16x4 bf = z4;
            if (g == 0) { bf[0]=fA[0]; bf[1]=fA[1]; bf[2]=fB[0]; bf[3]=fB[1]; }
            else if (g == 1) { bf[0] = (_Float16)1.f; }

            f32x4 e0 = zf, e1 = zf;
            #pragma unroll
            for (int s = 0; s < 16; ++s) {
                const f32x4 c1 = __builtin_amdgcn_mfma_f32_16x16x16f16(a1[s], bf, zf, 0, 0, 0);
                const h2 p01 = pkz(c1[0], c1[1]);   // RTZ on hidden
                const h2 p23 = pkz(c1[2], c1[3]);
                const h2 r01 = __builtin_elementwise_max(p01, zz);
                const h2 r23 = __builtin_elementwise_max(p23, zz);
                f16x4 hb;
                hb[0]=r01[0]; hb[1]=r01[1]; hb[2]=r23[0]; hb[3]=r23[1];
                if (s & 1) e1 = __builtin_amdgcn_mfma_f32_16x16x16f16(a2[s], hb, e1, 0, 0, 0);
                else       e0 = __builtin_amdgcn_mfma_f32_16x16x16f16(a2[s], hb, e0, 0, 0, 0);
            }
            if (l < 32) {
                #pragma unroll
                for (int r = 0; r < 4; ++r)
                    bw[i*132 + (g*4 + r)*16 + lo] = e0[r] + e1[r] + b2v[r] + km;
            }
        }

        asm volatile("s_waitcnt lgkmcnt(0)" ::: "memory");
        __builtin_amdgcn_sched_barrier(0);

        // merge QK (C: row i = g*4+r, col j = lo) into LDS logits
        #pragma unroll
        for (int h = 0; h < 8; ++h) {
            #pragma unroll
            for (int r = 0; r < 4; ++r)
                bw[(g*4 + r)*132 + h*16 + lo] += qk[h][r];
        }

        asm volatile("s_waitcnt lgkmcnt(0)" ::: "memory");
        __builtin_amdgcn_sched_barrier(0);

        // pack f16 j-pairs and store: iter u = query row i; lane -> (h, jp)
        {
            const int hh = (l >> 3) & 7;
            const int jp = l & 7;
            #pragma unroll
            for (int u = 0; u < 16; ++u) {
                const float2 v2 = *(const float2*)&bw[u*132 + hh*16 + 2*jp];
                logitsH[((size_t)((b*NN + i0 + u)*HH + hh))*(NN/2) + (jb >> 1) + jp] =
                    pk2u(v2.x, v2.y);
            }
        }
        asm volatile("s_waitcnt lgkmcnt(0)" ::: "memory");
        __builtin_amdgcn_sched_barrier(0);
    }
}

// ---------------- kernel B: softmax + PV ----------------
__global__ __launch_bounds__(256, 4) void attn_sm(
    const unsigned* __restrict__ logitsH, const unsigned* __restrict__ v16p,
    float* __restrict__ ao)
{
    __shared__ unsigned Lgh[16][260];
    __shared__ float red[16][16];
    __shared__ float mx[16];
    __shared__ float rs[16];

    const int t  = threadIdx.x;
    const int b  = blockIdx.x / (NN/2);
    const int i0 = (blockIdx.x % (NN/2)) * 2;

    #pragma unroll
    for (int ii = 0; ii < 2; ++ii)
        #pragma unroll
        for (int hh = 0; hh < HH; ++hh)
            Lgh[ii*8 + hh][t] = logitsH[((size_t)((b*NN + i0 + ii)*HH + hh))*(NN/2) + t];
    __syncthreads();

    const int combo = t >> 4;
    const int sub   = t & 15;
    {
        h2 pm = u2h(0xFC00FC00u);
        for (int jp = sub; jp < NN/2; jp += 16)
            pm = __builtin_elementwise_max(pm, u2h(Lgh[combo][jp]));
        red[combo][sub] = fmaxf((float)pm[0], (float)pm[1]);
    }
    __syncthreads();
    if (t < 16) {
        float mm = red[t][0];
        #pragma unroll
        for (int s = 1; s < 16; ++s) mm = fmaxf(mm, red[t][s]);
        mx[t] = mm;
    }
    __syncthreads();
    {
        const float M = mx[combo];
        float s = 0.f;
        for (int jp = sub; jp < NN/2; jp += 16) {
            const h2 lg = u2h(Lgh[combo][jp]);
            const float e0 = __expf((float)lg[0] - M);
            const float e1 = __expf((float)lg[1] - M);
            s += e0 + e1;
            Lgh[combo][jp] = pk2u(e0, e1);
        }
        red[combo][sub] = s;
    }
    __syncthreads();
    if (t < 16) {
        float s = 0.f;
        #pragma unroll
        for (int ss = 0; ss < 16; ++ss) s += red[t][ss];
        rs[t] = 1.f / s;
    }
    __syncthreads();

    {
        const int c = t;
        const int hh = c >> 5;
        const unsigned* vb = v16p + (size_t)b*(NN/2)*DD + c;
        float o[2] = {0.f, 0.f};
        for (int jp = 0; jp < NN/2; ++jp) {
            const h2 vp = u2h(vb[(size_t)jp*DD]);
            #pragma unroll
            for (int ii = 0; ii < 2; ++ii)
                o[ii] = dot2(u2h(Lgh[ii*8 + hh][jp]), vp, o[ii]);
        }
        #pragma unroll
        for (int ii = 0; ii < 2; ++ii)
            ao[(size_t)(b*NN + i0 + ii)*DD + c] = o[ii] * rs[ii*8 + hh];
    }
}

// ---------------- output projection ----------------
__global__ __launch_bounds__(256) void oproj(
    const float* __restrict__ X, const float* __restrict__ W, float* __restrict__ Y)
{
    __shared__ float xsT[DD][RB];
    const int t = threadIdx.x;
    const int r0 = blockIdx.x * RB;
    #pragma unroll
    for (int rr = 0; rr < RB; ++rr)
        xsT[t][rr] = X[(size_t)(r0 + rr)*DD + t];
    __syncthreads();
    float a[RB];
    #pragma unroll
    for (int rr = 0; rr < RB; ++rr) a[rr] = 0.f;
    for (int d = 0; d < DD; ++d) {
        const float w = W[d*DD + t];
        const float4 h0 = *(const float4*)&xsT[d][0];
        const float hv[4] = {h0.x, h0.y, h0.z, h0.w};
        #pragma unroll
        for (int rr = 0; rr < RB; ++rr)
            a[rr] = fmaf(hv[rr], w, a[rr]);
    }
    #pragma unroll
    for (int rr = 0; rr < RB; ++rr)
        Y[(size_t)(r0 + rr)*DD + t] = a[rr];
}

extern "C" void kernel_launch(void* const* d_in, const int* in_sizes, int n_in,
                              void* d_out, int out_size, void* d_ws, size_t ws_size,
                              hipStream_t stream) {
    const float* hg   = (const float*)d_in[0];
    const float* p    = (const float*)d_in[1];
    const int*   side = (const int*)d_in[2];
    const int*   mask = (const int*)d_in[3];
    const float* Wq   = (const float*)d_in[4];
    const float* Wk   = (const float*)d_in[5];
    const float* Wv   = (const float*)d_in[6];
    const float* Wo   = (const float*)d_in[7];
    const float* W1   = (const float*)d_in[8];
    const float* b1   = (const float*)d_in[9];
    const float* W2   = (const float*)d_in[10];
    const float* b2   = (const float*)d_in[11];

    float* ws = (float*)d_ws;
    float* ao = ws;                                   // BND f32
    _Float16* q16 = (_Float16*)(ws + BND);            // BND f16
    _Float16* k16 = q16 + BND;                        // BND f16
    _Float16* v16 = k16 + BND;                        // BND f16 (packed pairs)
    unsigned* logitsH = (unsigned*)(v16 + BND);       // B*N*H*(N/2) dwords

    qkv_proj<<<(BB*NN)/RB, 256, 0, stream>>>(hg, mask, Wq, Wk, Wv, q16, k16, v16);
    bias_qk<<<512, 256, 0, stream>>>(q16, k16, p, side, mask, W1, b1, W2, b2, logitsH);
    attn_sm<<<BB*(NN/2), 256, 0, stream>>>(logitsH, (const unsigned*)v16, ao);
    oproj<<<(BB*NN)/RB, 256, 0, stream>>>(ao, Wo, (float*)d_out);
}

// Round 12
// 99.171 us; speedup vs baseline: 2.0518x; 1.0244x over previous
//
#include <hip/hip_runtime.h>
#include <math.h>

#define BB 4
#define NN 512
#define DD 256
#define HH 8
#define BND (BB*NN*DD)

typedef _Float16 h2 __attribute__((ext_vector_type(2)));
typedef _Float16 f16x4 __attribute__((ext_vector_type(4)));
typedef float    f32x4 __attribute__((ext_vector_type(4)));

static __device__ __forceinline__ h2 u2h(unsigned u) { return __builtin_bit_cast(h2, u); }
// RNE pack (features/logits/GEMM inputs)
static __device__ __forceinline__ h2 pk2(float a, float b) {
    h2 r; r[0] = (_Float16)a; r[1] = (_Float16)b; return r;
}
static __device__ __forceinline__ unsigned pk2u(float a, float b) {
    return __builtin_bit_cast(unsigned, pk2(a, b));
}
// RTZ pack (hidden only — R9-proven)
static __device__ __forceinline__ h2 pkz(float a, float b) {
    return __builtin_bit_cast(h2, __builtin_amdgcn_cvt_pkrtz(a, b));
}
static __device__ __forceinline__ float dot2(h2 a, h2 b, float c) {
    return __builtin_amdgcn_fdot2(a, b, c, false);
}

// ---------------- pack: Wt[1024][256] f16, Wt[n][k] = W*[k][n] ----------------
// n: 0..255 Wq, 256..511 Wk, 512..767 Wv, 768..1023 Wo. LDS transpose, coalesced.
__global__ __launch_bounds__(256) void pack_wt(
    const float* __restrict__ Wq, const float* __restrict__ Wk,
    const float* __restrict__ Wv, const float* __restrict__ Wo,
    _Float16* __restrict__ wt)
{
    __shared__ float T[64][65];
    const int t  = threadIdx.x;
    const int nb = blockIdx.x >> 2;   // 16 n-blocks of 64
    const int kb = blockIdx.x & 3;    // 4 k-blocks of 64
    const int tn = t & 63;
    const int tr = t >> 6;
    const int nbase = nb * 64;
    const float* W = (nbase < 256) ? Wq : (nbase < 512) ? Wk : (nbase < 768) ? Wv : Wo;
    const int noff = nbase & 255;
    #pragma unroll
    for (int r = 0; r < 16; ++r) {
        const int kl = tr*16 + r;
        T[kl][tn] = W[(size_t)(kb*64 + kl)*DD + noff + tn];
    }
    __syncthreads();
    #pragma unroll
    for (int r = 0; r < 16; ++r) {
        const int nl = tr*16 + r;
        wt[(size_t)(nbase + nl)*DD + kb*64 + tn] = (_Float16)T[tn][nl];
    }
}

// ---------------- qkv via MFMA: [q|k|v] = (mask? h:0) @ [Wq|Wk|Wv] ----------------
// 1 wave/block, 16 rows x 32 cols per wave. A: row=lo, k=g*4+reg (h, RNE->f16,
// masked). B: col=lo, k=g*4+reg (wt rows, contiguous f16x4). C: row=g*4+r, col=lo.
__global__ __launch_bounds__(64) void gemm_qkv(
    const float* __restrict__ hg, const int* __restrict__ mask,
    const _Float16* __restrict__ wt,
    _Float16* __restrict__ q16, _Float16* __restrict__ k16, _Float16* __restrict__ v16h)
{
    const int l  = threadIdx.x;
    const int lo = l & 15, g = l >> 4;
    const int bid = blockIdx.x;         // 128 row-tiles x 24 col-tiles
    const int rt = bid / 24, ct = bid % 24;
    const int R0 = rt*16, C0 = ct*32;
    const int row = R0 + lo;
    const float msc = (mask[row] != 0) ? 1.f : 0.f;

    const float*    xrow = hg + (size_t)row*DD;
    const _Float16* w0   = wt + (size_t)(C0 + lo)*DD;
    const _Float16* w1   = wt + (size_t)(C0 + 16 + lo)*DD;
    f32x4 ac0 = {0.f,0.f,0.f,0.f}, ac1 = {0.f,0.f,0.f,0.f};
    #pragma unroll
    for (int kk = 0; kk < 16; ++kk) {
        const float4 xv = *(const float4*)(xrow + kk*16 + g*4);
        f16x4 a;
        a[0] = (_Float16)(xv.x * msc);
        a[1] = (_Float16)(xv.y * msc);
        a[2] = (_Float16)(xv.z * msc);
        a[3] = (_Float16)(xv.w * msc);
        const f16x4 b0 = *(const f16x4*)(w0 + kk*16 + g*4);
        const f16x4 b1 = *(const f16x4*)(w1 + kk*16 + g*4);
        ac0 = __builtin_amdgcn_mfma_f32_16x16x16f16(a, b0, ac0, 0, 0, 0);
        ac1 = __builtin_amdgcn_mfma_f32_16x16x16f16(a, b1, ac1, 0, 0, 0);
    }
    const float qscale = 0.17677669529663687f; // 1/sqrt(32)
    #pragma unroll
    for (int ci = 0; ci < 2; ++ci) {
        const f32x4 ac = ci ? ac1 : ac0;
        const int col = C0 + ci*16 + lo;
        const int seg = col >> 8;          // 0=q 1=k 2=v (tiles never straddle)
        const int cc  = col & 255;
        #pragma unroll
        for (int r = 0; r < 4; ++r) {
            const int ro = R0 + g*4 + r;
            const float val = ac[r];
            if (seg == 0)      q16[(size_t)ro*DD + cc] = (_Float16)val;
            else if (seg == 1) k16[(size_t)ro*DD + cc] = (_Float16)(val * qscale);
            else               v16h[((size_t)(ro >> 1)*DD + cc)*2 + (ro & 1)] = (_Float16)val;
        }
    }
}

// ---------------- kernel A: bias-MLP + QK, i-tile=16, all-MFMA ----------------
// block = (b, i-tile of 16, j-eighth of 64). 1024 blocks, 4 waves; wave w owns
// exactly one j-tile of 16. 4 blocks/CU (LDS 34KB).
__global__ __launch_bounds__(256, 4) void bias_qk(
    const _Float16* __restrict__ q16, const _Float16* __restrict__ k16,
    const float* __restrict__ p, const int* __restrict__ side, const int* __restrict__ mask,
    const float* __restrict__ W1, const float* __restrict__ b1,
    const float* __restrict__ W2, const float* __restrict__ b2,
    unsigned* __restrict__ logitsH)
{
    __shared__ float bsm[4][16*132];   // per-wave logits [i][h*16 + j], stride 132
    __shared__ float pis[16][2];
    __shared__ int   sis[16];

    const int t  = threadIdx.x;
    const int w  = t >> 6;
    const int l  = t & 63;
    const int lo = l & 15;
    const int g  = l >> 4;

    const int bid = blockIdx.x;
    const int b   = bid >> 8;
    const int it  = (bid >> 3) & 31;
    const int je  = bid & 7;
    const int i0  = it * 16;
    const int j0  = je * 64;

    if (t < 16) {
        const float2 pp = ((const float2*)p)[b*NN + i0 + t];
        pis[t][0] = pp.x; pis[t][1] = pp.y;
        sis[t] = side[b*NN + i0 + t];
    }
    __syncthreads();

    const f16x4 z4 = {(_Float16)0.f,(_Float16)0.f,(_Float16)0.f,(_Float16)0.f};
    const f32x4 zf = {0.f,0.f,0.f,0.f};
    const h2 zz = {(_Float16)0.f, (_Float16)0.f};

    // A1: W1ext^T[hid][k]  (k: 0..3 feats, 4 bias-one, 5..15 zero)
    f16x4 a1[16];
    #pragma unroll
    for (int m = 0; m < 16; ++m) {
        const int hid = m*16 + lo;
        f16x4 v = z4;
        const float w0 = W1[hid], w1 = W1[256+hid], w2 = W1[512+hid], w3 = W1[768+hid];
        const float bb1 = b1[hid];
        if (g == 0) { v[0]=(_Float16)w0; v[1]=(_Float16)w1; v[2]=(_Float16)w2; v[3]=(_Float16)w3; }
        else if (g == 1) { v[0]=(_Float16)bb1; }
        a1[m] = v;
    }
    // A2: W2^T[h][hid], rows 8..15 zero
    f16x4 a2[16];
    #pragma unroll
    for (int s = 0; s < 16; ++s) {
        const int kb4 = s*16 + g*4;
        const int hs  = lo & 7;
        f16x4 v;
        v[0] = (_Float16)W2[(kb4+0)*HH + hs];
        v[1] = (_Float16)W2[(kb4+1)*HH + hs];
        v[2] = (_Float16)W2[(kb4+2)*HH + hs];
        v[3] = (_Float16)W2[(kb4+3)*HH + hs];
        a2[s] = (lo < 8) ? v : z4;
    }
    // b2 addend for epilogue rows h = g*4+r (only l<32 stores)
    float b2v[4];
    #pragma unroll
    for (int r = 0; r < 4; ++r) b2v[r] = (g < 2) ? b2[(g*4 + r) & 7] : 0.f;

    // q A-fragments (row i = i0+lo, k = g*4+reg within 16-slice), once per block
    const _Float16* qbase = q16 + (size_t)(b*NN + i0 + lo)*DD;
    f16x4 qf[8][2];
    #pragma unroll
    for (int h = 0; h < 8; ++h) {
        qf[h][0] = *(const f16x4*)(qbase + h*32 + g*4);
        qf[h][1] = *(const f16x4*)(qbase + h*32 + 16 + g*4);
    }

    float* bw = &bsm[w][0];

    for (int jt = w; jt < 4; jt += 4) {
        const int jb = j0 + jt*16;
        const int j  = jb + lo;                 // this lane's key column

        const _Float16* kbase = k16 + (size_t)(b*NN + j)*DD;
        const float2 pj = ((const float2*)p)[b*NN + j];
        const int   sj  = side[b*NN + j];
        const float km  = mask[b*NN + j] ? 0.f : -3.0e4f;

        // QK: 8 heads x (K=32 as 2 MFMA). B: col j = lo, k = g*4+reg.
        f32x4 qk[8];
        #pragma unroll
        for (int h = 0; h < 8; ++h) {
            const f16x4 kf0 = *(const f16x4*)(kbase + h*32 + g*4);
            const f16x4 kf1 = *(const f16x4*)(kbase + h*32 + 16 + g*4);
            f32x4 a = __builtin_amdgcn_mfma_f32_16x16x16f16(qf[h][0], kf0, zf, 0, 0, 0);
            qk[h]   = __builtin_amdgcn_mfma_f32_16x16x16f16(qf[h][1], kf1, a, 0, 0, 0);
        }

        // MLP pair-groups: group = query row i, cols = 16 j
        #pragma unroll 4
        for (int i = 0; i < 16; ++i) {
            const float pix = pis[i][0], piy = pis[i][1];
            const int   sii = sis[i];
            const float dx = pix - pj.x;
            const float dy = piy - pj.y;
            const float di = fmaxf(sqrtf(dx*dx + dy*dy), 1e-6f);
            const float tm = (sii == sj) ? 1.f : 0.f;
            const h2 fA = pk2(dx, dy);   // RNE on features
            const h2 fB = pk2(di, tm);
            f16x4 bf = z4;
            if (g == 0) { bf[0]=fA[0]; bf[1]=fA[1]; bf[2]=fB[0]; bf[3]=fB[1]; }
            else if (g == 1) { bf[0] = (_Float16)1.f; }

            f32x4 e0 = zf, e1 = zf;
            #pragma unroll
            for (int s = 0; s < 16; ++s) {
                const f32x4 c1 = __builtin_amdgcn_mfma_f32_16x16x16f16(a1[s], bf, zf, 0, 0, 0);
                const h2 p01 = pkz(c1[0], c1[1]);   // RTZ on hidden
                const h2 p23 = pkz(c1[2], c1[3]);
                const h2 r01 = __builtin_elementwise_max(p01, zz);
                const h2 r23 = __builtin_elementwise_max(p23, zz);
                f16x4 hb;
                hb[0]=r01[0]; hb[1]=r01[1]; hb[2]=r23[0]; hb[3]=r23[1];
                if (s & 1) e1 = __builtin_amdgcn_mfma_f32_16x16x16f16(a2[s], hb, e1, 0, 0, 0);
                else       e0 = __builtin_amdgcn_mfma_f32_16x16x16f16(a2[s], hb, e0, 0, 0, 0);
            }
            if (l < 32) {
                #pragma unroll
                for (int r = 0; r < 4; ++r)
                    bw[i*132 + (g*4 + r)*16 + lo] = e0[r] + e1[r] + b2v[r] + km;
            }
        }

        asm volatile("s_waitcnt lgkmcnt(0)" ::: "memory");
        __builtin_amdgcn_sched_barrier(0);

        // merge QK (C: row i = g*4+r, col j = lo) into LDS logits
        #pragma unroll
        for (int h = 0; h < 8; ++h) {
            #pragma unroll
            for (int r = 0; r < 4; ++r)
                bw[(g*4 + r)*132 + h*16 + lo] += qk[h][r];
        }

        asm volatile("s_waitcnt lgkmcnt(0)" ::: "memory");
        __builtin_amdgcn_sched_barrier(0);

        // pack f16 j-pairs and store: iter u = query row i; lane -> (h, jp)
        {
            const int hh = (l >> 3) & 7;
            const int jp = l & 7;
            #pragma unroll
            for (int u = 0; u < 16; ++u) {
                const float2 v2 = *(const float2*)&bw[u*132 + hh*16 + 2*jp];
                logitsH[((size_t)((b*NN + i0 + u)*HH + hh))*(NN/2) + (jb >> 1) + jp] =
                    pk2u(v2.x, v2.y);
            }
        }
        asm volatile("s_waitcnt lgkmcnt(0)" ::: "memory");
        __builtin_amdgcn_sched_barrier(0);
    }
}

// ---------------- kernel B: softmax + PV ----------------
__global__ __launch_bounds__(256, 4) void attn_sm(
    const unsigned* __restrict__ logitsH, const unsigned* __restrict__ v16p,
    float* __restrict__ ao)
{
    __shared__ unsigned Lgh[16][260];
    __shared__ float red[16][16];
    __shared__ float mx[16];
    __shared__ float rs[16];

    const int t  = threadIdx.x;
    const int b  = blockIdx.x / (NN/2);
    const int i0 = (blockIdx.x % (NN/2)) * 2;

    #pragma unroll
    for (int ii = 0; ii < 2; ++ii)
        #pragma unroll
        for (int hh = 0; hh < HH; ++hh)
            Lgh[ii*8 + hh][t] = logitsH[((size_t)((b*NN + i0 + ii)*HH + hh))*(NN/2) + t];
    __syncthreads();

    const int combo = t >> 4;
    const int sub   = t & 15;
    {
        h2 pm = u2h(0xFC00FC00u);
        for (int jp = sub; jp < NN/2; jp += 16)
            pm = __builtin_elementwise_max(pm, u2h(Lgh[combo][jp]));
        red[combo][sub] = fmaxf((float)pm[0], (float)pm[1]);
    }
    __syncthreads();
    if (t < 16) {
        float mm = red[t][0];
        #pragma unroll
        for (int s = 1; s < 16; ++s) mm = fmaxf(mm, red[t][s]);
        mx[t] = mm;
    }
    __syncthreads();
    {
        const float M = mx[combo];
        float s = 0.f;
        for (int jp = sub; jp < NN/2; jp += 16) {
            const h2 lg = u2h(Lgh[combo][jp]);
            const float e0 = __expf((float)lg[0] - M);
            const float e1 = __expf((float)lg[1] - M);
            s += e0 + e1;
            Lgh[combo][jp] = pk2u(e0, e1);
        }
        red[combo][sub] = s;
    }
    __syncthreads();
    if (t < 16) {
        float s = 0.f;
        #pragma unroll
        for (int ss = 0; ss < 16; ++ss) s += red[t][ss];
        rs[t] = 1.f / s;
    }
    __syncthreads();

    {
        const int c = t;
        const int hh = c >> 5;
        const unsigned* vb = v16p + (size_t)b*(NN/2)*DD + c;
        float o[2] = {0.f, 0.f};
        for (int jp = 0; jp < NN/2; ++jp) {
            const h2 vp = u2h(vb[(size_t)jp*DD]);
            #pragma unroll
            for (int ii = 0; ii < 2; ++ii)
                o[ii] = dot2(u2h(Lgh[ii*8 + hh][jp]), vp, o[ii]);
        }
        #pragma unroll
        for (int ii = 0; ii < 2; ++ii)
            ao[(size_t)(b*NN + i0 + ii)*DD + c] = o[ii] * rs[ii*8 + hh];
    }
}

// ---------------- output projection via MFMA: out = ao @ Wo ----------------
__global__ __launch_bounds__(64) void gemm_o(
    const float* __restrict__ X, const _Float16* __restrict__ wt,  // wt = Wo^T rows
    float* __restrict__ Y)
{
    const int l  = threadIdx.x;
    const int lo = l & 15, g = l >> 4;
    const int bid = blockIdx.x;         // 128 row-tiles x 8 col-tiles
    const int rt = bid >> 3, ct = bid & 7;
    const int R0 = rt*16, C0 = ct*32;
    const int row = R0 + lo;

    const float*    xrow = X + (size_t)row*DD;
    const _Float16* w0   = wt + (size_t)(C0 + lo)*DD;
    const _Float16* w1   = wt + (size_t)(C0 + 16 + lo)*DD;
    f32x4 ac0 = {0.f,0.f,0.f,0.f}, ac1 = {0.f,0.f,0.f,0.f};
    #pragma unroll
    for (int kk = 0; kk < 16; ++kk) {
        const float4 xv = *(const float4*)(xrow + kk*16 + g*4);
        f16x4 a;
        a[0] = (_Float16)xv.x;
        a[1] = (_Float16)xv.y;
        a[2] = (_Float16)xv.z;
        a[3] = (_Float16)xv.w;
        const f16x4 b0 = *(const f16x4*)(w0 + kk*16 + g*4);
        const f16x4 b1 = *(const f16x4*)(w1 + kk*16 + g*4);
        ac0 = __builtin_amdgcn_mfma_f32_16x16x16f16(a, b0, ac0, 0, 0, 0);
        ac1 = __builtin_amdgcn_mfma_f32_16x16x16f16(a, b1, ac1, 0, 0, 0);
    }
    #pragma unroll
    for (int ci = 0; ci < 2; ++ci) {
        const f32x4 ac = ci ? ac1 : ac0;
        const int col = C0 + ci*16 + lo;
        #pragma unroll
        for (int r = 0; r < 4; ++r)
            Y[(size_t)(R0 + g*4 + r)*DD + col] = ac[r];
    }
}

extern "C" void kernel_launch(void* const* d_in, const int* in_sizes, int n_in,
                              void* d_out, int out_size, void* d_ws, size_t ws_size,
                              hipStream_t stream) {
    const float* hg   = (const float*)d_in[0];
    const float* p    = (const float*)d_in[1];
    const int*   side = (const int*)d_in[2];
    const int*   mask = (const int*)d_in[3];
    const float* Wq   = (const float*)d_in[4];
    const float* Wk   = (const float*)d_in[5];
    const float* Wv   = (const float*)d_in[6];
    const float* Wo   = (const float*)d_in[7];
    const float* W1   = (const float*)d_in[8];
    const float* b1   = (const float*)d_in[9];
    const float* W2   = (const float*)d_in[10];
    const float* b2   = (const float*)d_in[11];

    float* ws = (float*)d_ws;
    float* ao = ws;                                   // BND f32
    _Float16* q16 = (_Float16*)(ws + BND);            // BND f16
    _Float16* k16 = q16 + BND;                        // BND f16
    _Float16* v16 = k16 + BND;                        // BND f16 (packed pairs)
    unsigned* logitsH = (unsigned*)(v16 + BND);       // B*N*H*(N/2) dwords
    _Float16* wt16 = (_Float16*)(logitsH + (size_t)BB*NN*HH*(NN/2));  // [1024][256]

    pack_wt<<<64, 256, 0, stream>>>(Wq, Wk, Wv, Wo, wt16);
    gemm_qkv<<<128*24, 64, 0, stream>>>(hg, mask, wt16, q16, k16, v16);
    bias_qk<<<1024, 256, 0, stream>>>(q16, k16, p, side, mask, W1, b1, W2, b2, logitsH);
    attn_sm<<<BB*(NN/2), 256, 0, stream>>>(logitsH, (const unsigned*)v16, ao);
    gemm_o<<<128*8, 64, 0, stream>>>(ao, wt16 + (size_t)768*DD, (float*)d_out);
}

// Round 13
// 91.711 us; speedup vs baseline: 2.2187x; 1.0813x over previous
//
#include <hip/hip_runtime.h>
#include <math.h>

#define BB 4
#define NN 512
#define DD 256
#define HH 8
#define BND (BB*NN*DD)

typedef _Float16 h2 __attribute__((ext_vector_type(2)));
typedef _Float16 f16x4 __attribute__((ext_vector_type(4)));
typedef float    f32x4 __attribute__((ext_vector_type(4)));

static __device__ __forceinline__ h2 u2h(unsigned u) { return __builtin_bit_cast(h2, u); }
// RNE pack (features/logits/GEMM inputs)
static __device__ __forceinline__ h2 pk2(float a, float b) {
    h2 r; r[0] = (_Float16)a; r[1] = (_Float16)b; return r;
}
static __device__ __forceinline__ unsigned pk2u(float a, float b) {
    return __builtin_bit_cast(unsigned, pk2(a, b));
}
// RTZ pack (hidden only — R9-proven)
static __device__ __forceinline__ h2 pkz(float a, float b) {
    return __builtin_bit_cast(h2, __builtin_amdgcn_cvt_pkrtz(a, b));
}
static __device__ __forceinline__ float dot2(h2 a, h2 b, float c) {
    return __builtin_amdgcn_fdot2(a, b, c, false);
}

// ---------------- pack: Wt[1024][256] f16, Wt[n][k] = W*[k][n] ----------------
__global__ __launch_bounds__(256) void pack_wt(
    const float* __restrict__ Wq, const float* __restrict__ Wk,
    const float* __restrict__ Wv, const float* __restrict__ Wo,
    _Float16* __restrict__ wt)
{
    __shared__ float T[64][65];
    const int t  = threadIdx.x;
    const int nb = blockIdx.x >> 2;   // 16 n-blocks of 64
    const int kb = blockIdx.x & 3;    // 4 k-blocks of 64
    const int tn = t & 63;
    const int tr = t >> 6;
    const int nbase = nb * 64;
    const float* W = (nbase < 256) ? Wq : (nbase < 512) ? Wk : (nbase < 768) ? Wv : Wo;
    const int noff = nbase & 255;
    #pragma unroll
    for (int r = 0; r < 16; ++r) {
        const int kl = tr*16 + r;
        T[kl][tn] = W[(size_t)(kb*64 + kl)*DD + noff + tn];
    }
    __syncthreads();
    #pragma unroll
    for (int r = 0; r < 16; ++r) {
        const int nl = tr*16 + r;
        wt[(size_t)(nbase + nl)*DD + kb*64 + tn] = (_Float16)T[tn][nl];
    }
}

// ---------------- qkv via MFMA ----------------
__global__ __launch_bounds__(64) void gemm_qkv(
    const float* __restrict__ hg, const int* __restrict__ mask,
    const _Float16* __restrict__ wt,
    _Float16* __restrict__ q16, _Float16* __restrict__ k16, _Float16* __restrict__ v16h)
{
    const int l  = threadIdx.x;
    const int lo = l & 15, g = l >> 4;
    const int bid = blockIdx.x;         // 128 row-tiles x 24 col-tiles
    const int rt = bid / 24, ct = bid % 24;
    const int R0 = rt*16, C0 = ct*32;
    const int row = R0 + lo;
    const float msc = (mask[row] != 0) ? 1.f : 0.f;

    const float*    xrow = hg + (size_t)row*DD;
    const _Float16* w0   = wt + (size_t)(C0 + lo)*DD;
    const _Float16* w1   = wt + (size_t)(C0 + 16 + lo)*DD;
    f32x4 ac0 = {0.f,0.f,0.f,0.f}, ac1 = {0.f,0.f,0.f,0.f};
    #pragma unroll
    for (int kk = 0; kk < 16; ++kk) {
        const float4 xv = *(const float4*)(xrow + kk*16 + g*4);
        f16x4 a;
        a[0] = (_Float16)(xv.x * msc);
        a[1] = (_Float16)(xv.y * msc);
        a[2] = (_Float16)(xv.z * msc);
        a[3] = (_Float16)(xv.w * msc);
        const f16x4 b0 = *(const f16x4*)(w0 + kk*16 + g*4);
        const f16x4 b1 = *(const f16x4*)(w1 + kk*16 + g*4);
        ac0 = __builtin_amdgcn_mfma_f32_16x16x16f16(a, b0, ac0, 0, 0, 0);
        ac1 = __builtin_amdgcn_mfma_f32_16x16x16f16(a, b1, ac1, 0, 0, 0);
    }
    const float qscale = 0.17677669529663687f; // 1/sqrt(32)
    #pragma unroll
    for (int ci = 0; ci < 2; ++ci) {
        const f32x4 ac = ci ? ac1 : ac0;
        const int col = C0 + ci*16 + lo;
        const int seg = col >> 8;          // 0=q 1=k 2=v
        const int cc  = col & 255;
        #pragma unroll
        for (int r = 0; r < 4; ++r) {
            const int ro = R0 + g*4 + r;
            const float val = ac[r];
            if (seg == 0)      q16[(size_t)ro*DD + cc] = (_Float16)val;
            else if (seg == 1) k16[(size_t)ro*DD + cc] = (_Float16)(val * qscale);
            else               v16h[((size_t)(ro >> 1)*DD + cc)*2 + (ro & 1)] = (_Float16)val;
        }
    }
}

// ---------------- kernel A: bias-MLP + QK, i-tile=16, all-MFMA ----------------
// block = (b, i-tile of 16, j-eighth of 64). 1024 blocks, 4 waves; wave w owns
// j-tile je*64 + w*16. QK deferred to after the MLP loop (register pressure:
// qf/qk never live across the i-loop -> no spill at launch_bounds(256,3)).
__global__ __launch_bounds__(256, 3) void bias_qk(
    const _Float16* __restrict__ q16, const _Float16* __restrict__ k16,
    const float* __restrict__ p, const int* __restrict__ side, const int* __restrict__ mask,
    const float* __restrict__ W1, const float* __restrict__ b1,
    const float* __restrict__ W2, const float* __restrict__ b2,
    unsigned* __restrict__ logitsH)
{
    __shared__ float bsm[4][16*132];   // per-wave logits [i][h*16 + j], stride 132
    __shared__ float pis[16][2];
    __shared__ int   sis[16];

    const int t  = threadIdx.x;
    const int w  = t >> 6;
    const int l  = t & 63;
    const int lo = l & 15;
    const int g  = l >> 4;

    const int bid = blockIdx.x;
    const int b   = bid >> 8;
    const int it  = (bid >> 3) & 31;
    const int je  = bid & 7;
    const int i0  = it * 16;
    const int jb  = je * 64 + w * 16;   // this wave's j-tile
    const int j   = jb + lo;            // this lane's key column

    if (t < 16) {
        const float2 pp = ((const float2*)p)[b*NN + i0 + t];
        pis[t][0] = pp.x; pis[t][1] = pp.y;
        sis[t] = side[b*NN + i0 + t];
    }
    __syncthreads();

    const f16x4 z4 = {(_Float16)0.f,(_Float16)0.f,(_Float16)0.f,(_Float16)0.f};
    const f32x4 zf = {0.f,0.f,0.f,0.f};
    const h2 zz = {(_Float16)0.f, (_Float16)0.f};

    // A1: W1ext^T[hid][k]  (k: 0..3 feats, 4 bias-one, 5..15 zero)
    f16x4 a1[16];
    #pragma unroll
    for (int m = 0; m < 16; ++m) {
        const int hid = m*16 + lo;
        f16x4 v = z4;
        const float w0 = W1[hid], w1 = W1[256+hid], w2 = W1[512+hid], w3 = W1[768+hid];
        const float bb1 = b1[hid];
        if (g == 0) { v[0]=(_Float16)w0; v[1]=(_Float16)w1; v[2]=(_Float16)w2; v[3]=(_Float16)w3; }
        else if (g == 1) { v[0]=(_Float16)bb1; }
        a1[m] = v;
    }
    // A2: W2^T[h][hid], rows 8..15 zero
    f16x4 a2[16];
    #pragma unroll
    for (int s = 0; s < 16; ++s) {
        const int kb4 = s*16 + g*4;
        const int hs  = lo & 7;
        f16x4 v;
        v[0] = (_Float16)W2[(kb4+0)*HH + hs];
        v[1] = (_Float16)W2[(kb4+1)*HH + hs];
        v[2] = (_Float16)W2[(kb4+2)*HH + hs];
        v[3] = (_Float16)W2[(kb4+3)*HH + hs];
        a2[s] = (lo < 8) ? v : z4;
    }
    // b2 addend for epilogue rows h = g*4+r (only l<32 stores)
    float b2v[4];
    #pragma unroll
    for (int r = 0; r < 4; ++r) b2v[r] = (g < 2) ? b2[(g*4 + r) & 7] : 0.f;

    const float2 pj = ((const float2*)p)[b*NN + j];
    const int   sj  = side[b*NN + j];
    const float km  = mask[b*NN + j] ? 0.f : -3.0e4f;

    float* bw = &bsm[w][0];

    // ---- MLP: 16 pair-groups (group = query row i, cols = 16 j) ----
    #pragma unroll 2
    for (int i = 0; i < 16; ++i) {
        const float pix = pis[i][0], piy = pis[i][1];
        const int   sii = sis[i];
        const float dx = pix - pj.x;
        const float dy = piy - pj.y;
        const float di = fmaxf(sqrtf(dx*dx + dy*dy), 1e-6f);
        const float tm = (sii == sj) ? 1.f : 0.f;
        const h2 fA = pk2(dx, dy);   // RNE on features
        const h2 fB = pk2(di, tm);
        f16x4 bf = z4;
        if (g == 0) { bf[0]=fA[0]; bf[1]=fA[1]; bf[2]=fB[0]; bf[3]=fB[1]; }
        else if (g == 1) { bf[0] = (_Float16)1.f; }

        f32x4 e0 = zf, e1 = zf;
        #pragma unroll
        for (int s = 0; s < 16; ++s) {
            const f32x4 c1 = __builtin_amdgcn_mfma_f32_16x16x16f16(a1[s], bf, zf, 0, 0, 0);
            const h2 p01 = pkz(c1[0], c1[1]);   // RTZ on hidden
            const h2 p23 = pkz(c1[2], c1[3]);
            const h2 r01 = __builtin_elementwise_max(p01, zz);
            const h2 r23 = __builtin_elementwise_max(p23, zz);
            f16x4 hb;
            hb[0]=r01[0]; hb[1]=r01[1]; hb[2]=r23[0]; hb[3]=r23[1];
            if (s & 1) e1 = __builtin_amdgcn_mfma_f32_16x16x16f16(a2[s], hb, e1, 0, 0, 0);
            else       e0 = __builtin_amdgcn_mfma_f32_16x16x16f16(a2[s], hb, e0, 0, 0, 0);
        }
        if (l < 32) {
            #pragma unroll
            for (int r = 0; r < 4; ++r)
                bw[i*132 + (g*4 + r)*16 + lo] = e0[r] + e1[r] + b2v[r] + km;
        }
    }

    asm volatile("s_waitcnt lgkmcnt(0)" ::: "memory");
    __builtin_amdgcn_sched_barrier(0);

    // ---- QK (deferred): per head, 2 MFMA (K=32) then merge into LDS ----
    {
        const _Float16* qbase = q16 + (size_t)(b*NN + i0 + lo)*DD;
        const _Float16* kbase = k16 + (size_t)(b*NN + j)*DD;
        #pragma unroll
        for (int h = 0; h < 8; ++h) {
            const f16x4 q0  = *(const f16x4*)(qbase + h*32 + g*4);
            const f16x4 q1  = *(const f16x4*)(qbase + h*32 + 16 + g*4);
            const f16x4 kf0 = *(const f16x4*)(kbase + h*32 + g*4);
            const f16x4 kf1 = *(const f16x4*)(kbase + h*32 + 16 + g*4);
            f32x4 a  = __builtin_amdgcn_mfma_f32_16x16x16f16(q0, kf0, zf, 0, 0, 0);
            f32x4 qk = __builtin_amdgcn_mfma_f32_16x16x16f16(q1, kf1, a, 0, 0, 0);
            // C: row i = g*4+r, col j = lo
            #pragma unroll
            for (int r = 0; r < 4; ++r)
                bw[(g*4 + r)*132 + h*16 + lo] += qk[r];
        }
    }

    asm volatile("s_waitcnt lgkmcnt(0)" ::: "memory");
    __builtin_amdgcn_sched_barrier(0);

    // ---- pack f16 j-pairs and store: iter u = query row i; lane -> (h, jp) ----
    {
        const int hh = (l >> 3) & 7;
        const int jp = l & 7;
        #pragma unroll
        for (int u = 0; u < 16; ++u) {
            const float2 v2 = *(const float2*)&bw[u*132 + hh*16 + 2*jp];
            logitsH[((size_t)((b*NN + i0 + u)*HH + hh))*(NN/2) + (jb >> 1) + jp] =
                pk2u(v2.x, v2.y);
        }
    }
}

// ---------------- kernel B: softmax + PV ----------------
__global__ __launch_bounds__(256, 4) void attn_sm(
    const unsigned* __restrict__ logitsH, const unsigned* __restrict__ v16p,
    float* __restrict__ ao)
{
    __shared__ unsigned Lgh[16][260];
    __shared__ float red[16][16];
    __shared__ float mx[16];
    __shared__ float rs[16];

    const int t  = threadIdx.x;
    const int b  = blockIdx.x / (NN/2);
    const int i0 = (blockIdx.x % (NN/2)) * 2;

    #pragma unroll
    for (int ii = 0; ii < 2; ++ii)
        #pragma unroll
        for (int hh = 0; hh < HH; ++hh)
            Lgh[ii*8 + hh][t] = logitsH[((size_t)((b*NN + i0 + ii)*HH + hh))*(NN/2) + t];
    __syncthreads();

    const int combo = t >> 4;
    const int sub   = t & 15;
    {
        h2 pm = u2h(0xFC00FC00u);
        for (int jp = sub; jp < NN/2; jp += 16)
            pm = __builtin_elementwise_max(pm, u2h(Lgh[combo][jp]));
        red[combo][sub] = fmaxf((float)pm[0], (float)pm[1]);
    }
    __syncthreads();
    if (t < 16) {
        float mm = red[t][0];
        #pragma unroll
        for (int s = 1; s < 16; ++s) mm = fmaxf(mm, red[t][s]);
        mx[t] = mm;
    }
    __syncthreads();
    {
        const float M = mx[combo];
        float s = 0.f;
        for (int jp = sub; jp < NN/2; jp += 16) {
            const h2 lg = u2h(Lgh[combo][jp]);
            const float e0 = __expf((float)lg[0] - M);
            const float e1 = __expf((float)lg[1] - M);
            s += e0 + e1;
            Lgh[combo][jp] = pk2u(e0, e1);
        }
        red[combo][sub] = s;
    }
    __syncthreads();
    if (t < 16) {
        float s = 0.f;
        #pragma unroll
        for (int ss = 0; ss < 16; ++ss) s += red[t][ss];
        rs[t] = 1.f / s;
    }
    __syncthreads();

    {
        const int c = t;
        const int hh = c >> 5;
        const unsigned* vb = v16p + (size_t)b*(NN/2)*DD + c;
        float o[2] = {0.f, 0.f};
        for (int jp = 0; jp < NN/2; ++jp) {
            const h2 vp = u2h(vb[(size_t)jp*DD]);
            #pragma unroll
            for (int ii = 0; ii < 2; ++ii)
                o[ii] = dot2(u2h(Lgh[ii*8 + hh][jp]), vp, o[ii]);
        }
        #pragma unroll
        for (int ii = 0; ii < 2; ++ii)
            ao[(size_t)(b*NN + i0 + ii)*DD + c] = o[ii] * rs[ii*8 + hh];
    }
}

// ---------------- output projection via MFMA ----------------
__global__ __launch_bounds__(64) void gemm_o(
    const float* __restrict__ X, const _Float16* __restrict__ wt,
    float* __restrict__ Y)
{
    const int l  = threadIdx.x;
    const int lo = l & 15, g = l >> 4;
    const int bid = blockIdx.x;         // 128 row-tiles x 8 col-tiles
    const int rt = bid >> 3, ct = bid & 7;
    const int R0 = rt*16, C0 = ct*32;
    const int row = R0 + lo;

    const float*    xrow = X + (size_t)row*DD;
    const _Float16* w0   = wt + (size_t)(C0 + lo)*DD;
    const _Float16* w1   = wt + (size_t)(C0 + 16 + lo)*DD;
    f32x4 ac0 = {0.f,0.f,0.f,0.f}, ac1 = {0.f,0.f,0.f,0.f};
    #pragma unroll
    for (int kk = 0; kk < 16; ++kk) {
        const float4 xv = *(const float4*)(xrow + kk*16 + g*4);
        f16x4 a;
        a[0] = (_Float16)xv.x;
        a[1] = (_Float16)xv.y;
        a[2] = (_Float16)xv.z;
        a[3] = (_Float16)xv.w;
        const f16x4 b0 = *(const f16x4*)(w0 + kk*16 + g*4);
        const f16x4 b1 = *(const f16x4*)(w1 + kk*16 + g*4);
        ac0 = __builtin_amdgcn_mfma_f32_16x16x16f16(a, b0, ac0, 0, 0, 0);
        ac1 = __builtin_amdgcn_mfma_f32_16x16x16f16(a, b1, ac1, 0, 0, 0);
    }
    #pragma unroll
    for (int ci = 0; ci < 2; ++ci) {
        const f32x4 ac = ci ? ac1 : ac0;
        const int col = C0 + ci*16 + lo;
        #pragma unroll
        for (int r = 0; r < 4; ++r)
            Y[(size_t)(R0 + g*4 + r)*DD + col] = ac[r];
    }
}

extern "C" void kernel_launch(void* const* d_in, const int* in_sizes, int n_in,
                              void* d_out, int out_size, void* d_ws, size_t ws_size,
                              hipStream_t stream) {
    const float* hg   = (const float*)d_in[0];
    const float* p    = (const float*)d_in[1];
    const int*   side = (const int*)d_in[2];
    const int*   mask = (const int*)d_in[3];
    const float* Wq   = (const float*)d_in[4];
    const float* Wk   = (const float*)d_in[5];
    const float* Wv   = (const float*)d_in[6];
    const float* Wo   = (const float*)d_in[7];
    const float* W1   = (const float*)d_in[8];
    const float* b1   = (const float*)d_in[9];
    const float* W2   = (const float*)d_in[10];
    const float* b2   = (const float*)d_in[11];

    float* ws = (float*)d_ws;
    float* ao = ws;                                   // BND f32
    _Float16* q16 = (_Float16*)(ws + BND);            // BND f16
    _Float16* k16 = q16 + BND;                        // BND f16
    _Float16* v16 = k16 + BND;                        // BND f16 (packed pairs)
    unsigned* logitsH = (unsigned*)(v16 + BND);       // B*N*H*(N/2) dwords
    _Float16* wt16 = (_Float16*)(logitsH + (size_t)BB*NN*HH*(NN/2));  // [1024][256]

    pack_wt<<<64, 256, 0, stream>>>(Wq, Wk, Wv, Wo, wt16);
    gemm_qkv<<<128*24, 64, 0, stream>>>(hg, mask, wt16, q16, k16, v16);
    bias_qk<<<1024, 256, 0, stream>>>(q16, k16, p, side, mask, W1, b1, W2, b2, logitsH);
    attn_sm<<<BB*(NN/2), 256, 0, stream>>>(logitsH, (const unsigned*)v16, ao);
    gemm_o<<<128*8, 64, 0, stream>>>(ao, wt16 + (size_t)768*DD, (float*)d_out);
}